// Round 1
// baseline (254.268 us; speedup 1.0000x reference)
//
#include <hip/hip_runtime.h>

// PaDiM training-branch accumulation + finalize.
// embeddings: [B=32, C=192, P=3136] f32
// means:      [P, C] f32 (running sums)
// covariances:[P, C, C] f32 (running outer-product sums)
// n:          int scalar (96)
// out: learned_means [P,C] ++ learned_covs [P,C,C]

#define BB 32
#define CC 192
#define PP 3136
#define EPSV 0.01f

__global__ __launch_bounds__(256) void padim_kernel(
    const float* __restrict__ emb,    // [B,C,P]
    const float* __restrict__ means,  // [P,C]
    const float* __restrict__ covs,   // [P,C,C]
    const int*   __restrict__ n_ptr,  // [1]
    float* __restrict__ out_means,    // [P,C]
    float* __restrict__ out_covs)     // [P,C,C]
{
    // E rows padded to 196 floats (784 B = 49*16B) so float4 loads stay aligned.
    __shared__ __align__(16) float E[BB][CC + 4];
    __shared__ __align__(16) float m[CC];

    // XCD-aware swizzle: 3136 blocks, 8 XCDs -> XCD x owns contiguous 392 patches.
    const int bid = blockIdx.x;
    const int p = (bid & 7) * (PP / 8) + (bid >> 3);

    const int t = threadIdx.x;

    const float n_new = (float)(n_ptr[0] + BB);       // 128
    const float inv_nnew = 1.0f / n_new;
    const float inv_nm1 = 1.0f / (n_new - 1.0f);      // 1/127

    // ---- Stage E[b][c] = emb[b, c, p] into LDS ----
    // flat idx i = b*C + c  ->  emb[i*P + p]  (strided gather; L2/L3 absorb reuse
    // since each 64B line covers 16 consecutive patches on the same XCD).
    #pragma unroll
    for (int i = t; i < BB * CC; i += 256) {
        const int b = i / CC;
        const int c = i - b * CC;
        E[b][c] = emb[(size_t)i * PP + p];
    }
    __syncthreads();

    // ---- Means: m[c] = (means[p,c] + sum_b E[b][c]) / n_new ----
    if (t < CC) {
        float s = 0.0f;
        #pragma unroll
        for (int b = 0; b < BB; ++b) s += E[b][t];
        const float mm = (means[(size_t)p * CC + t] + s) * inv_nnew;
        m[t] = mm;
        out_means[(size_t)p * CC + t] = mm;
    }
    __syncthreads();

    // ---- Covariance: 9 passes of 64x64 tiles, 16x16 threads, 4x4 micro-tile ----
    const int tx = t & 15;   // d dimension
    const int ty = t >> 4;   // c dimension
    const float* __restrict__ cov_p = covs + (size_t)p * CC * CC;
    float* __restrict__ out_p = out_covs + (size_t)p * CC * CC;

    #pragma unroll 1
    for (int pass = 0; pass < 9; ++pass) {
        const int tc = pass / 3;
        const int td = pass - tc * 3;
        const int c0 = tc * 64 + ty * 4;
        const int d0 = td * 64 + tx * 4;

        float acc[4][4] = {{0.f,0.f,0.f,0.f},{0.f,0.f,0.f,0.f},
                           {0.f,0.f,0.f,0.f},{0.f,0.f,0.f,0.f}};

        #pragma unroll 8
        for (int b = 0; b < BB; ++b) {
            const float4 cv = *reinterpret_cast<const float4*>(&E[b][c0]);
            const float4 dv = *reinterpret_cast<const float4*>(&E[b][d0]);
            const float cs[4] = {cv.x, cv.y, cv.z, cv.w};
            const float ds[4] = {dv.x, dv.y, dv.z, dv.w};
            #pragma unroll
            for (int i = 0; i < 4; ++i)
                #pragma unroll
                for (int j = 0; j < 4; ++j)
                    acc[i][j] = fmaf(cs[i], ds[j], acc[i][j]);
        }

        const float4 mc4 = *reinterpret_cast<const float4*>(&m[c0]);
        const float4 md4 = *reinterpret_cast<const float4*>(&m[d0]);
        const float mcs[4] = {mc4.x, mc4.y, mc4.z, mc4.w};
        const float mds[4] = {md4.x, md4.y, md4.z, md4.w};

        #pragma unroll
        for (int i = 0; i < 4; ++i) {
            const int c = c0 + i;
            const size_t row = (size_t)c * CC + d0;
            const float4 cin = *reinterpret_cast<const float4*>(&cov_p[row]);
            const float nm_c = n_new * mcs[i];
            float4 o;
            o.x = (cin.x + acc[i][0] - nm_c * mds[0]) * inv_nm1;
            o.y = (cin.y + acc[i][1] - nm_c * mds[1]) * inv_nm1;
            o.z = (cin.z + acc[i][2] - nm_c * mds[2]) * inv_nm1;
            o.w = (cin.w + acc[i][3] - nm_c * mds[3]) * inv_nm1;
            if (c == d0 + 0) o.x += EPSV;
            if (c == d0 + 1) o.y += EPSV;
            if (c == d0 + 2) o.z += EPSV;
            if (c == d0 + 3) o.w += EPSV;
            *reinterpret_cast<float4*>(&out_p[row]) = o;
        }
    }
}

extern "C" void kernel_launch(void* const* d_in, const int* in_sizes, int n_in,
                              void* d_out, int out_size, void* d_ws, size_t ws_size,
                              hipStream_t stream) {
    const float* emb   = (const float*)d_in[0];
    const float* means = (const float*)d_in[1];
    const float* covs  = (const float*)d_in[2];
    const int*   n_ptr = (const int*)d_in[3];

    float* out_means = (float*)d_out;                      // [P,C]
    float* out_covs  = (float*)d_out + (size_t)PP * CC;    // [P,C,C]

    hipLaunchKernelGGL(padim_kernel, dim3(PP), dim3(256), 0, stream,
                       emb, means, covs, n_ptr, out_means, out_covs);
}